// Round 3
// baseline (386.727 us; speedup 1.0000x reference)
//
#include <hip/hip_runtime.h>
#include <math.h>

// Problem constants
#define BB 2
#define LL 1024
#define HIDD 1024
#define NH 4
#define DD 256
#define NCH 32
#define ROWS 2048
#define HROWS 8192

typedef long long i64;
typedef unsigned short u16t;
typedef unsigned int u32t;
typedef __attribute__((ext_vector_type(8))) short short8;
typedef __attribute__((ext_vector_type(4))) float f32x4;
#define MFMA_BF16(a, b, c) __builtin_amdgcn_mfma_f32_16x16x32_bf16(a, b, c, 0, 0, 0)

__device__ __forceinline__ float sigmoidf_(float x) { return 1.0f / (1.0f + expf(-x)); }

__device__ __forceinline__ u16t f2bf(float f) {
  u32t u = __float_as_uint(f);
  u = u + 0x7FFFu + ((u >> 16) & 1u);
  return (u16t)(u >> 16);
}
__device__ __forceinline__ u32t pk2(u16t a, u16t b) { return (u32t)a | ((u32t)b << 16); }

// HW packed f32->bf16 RNE convert (gfx950): 1 instr vs 6-op bit-trick pair.
// Identical rounding to f2bf for finite values (both RNE).
__device__ __forceinline__ u32t cvt_pk_bf16(float lo, float hi) {
  u32t r;
  asm("v_cvt_pk_bf16_f32 %0, %1, %2" : "=v"(r) : "v"(lo), "v"(hi));
  return r;
}

// counted-wait barrier: drain only LDS ops (cross-wave visibility of ds_writes),
// keep global prefetch loads in flight across the barrier.
__device__ __forceinline__ void barrier_lds_only() {
  asm volatile("s_waitcnt lgkmcnt(0)" ::: "memory");
  __builtin_amdgcn_s_barrier();
  asm volatile("" ::: "memory");  // fence: no loads hoisted above the barrier
}

// ---------------- block reduction helpers (blockDim == 256) ----------------
template<int N>
__device__ __forceinline__ void block_reduce_sum(float* v, float* scratch) {
  int lane = threadIdx.x & 63, wid = threadIdx.x >> 6;
#pragma unroll
  for (int i = 0; i < N; i++) {
    float x = v[i];
#pragma unroll
    for (int off = 1; off < 64; off <<= 1) x += __shfl_xor(x, off);
    if (lane == 0) scratch[wid * N + i] = x;
  }
  __syncthreads();
#pragma unroll
  for (int i = 0; i < N; i++)
    v[i] = scratch[i] + scratch[N + i] + scratch[2 * N + i] + scratch[3 * N + i];
  __syncthreads();
}

template<int N>
__device__ __forceinline__ void block_reduce_max(float* v, float* scratch) {
  int lane = threadIdx.x & 63, wid = threadIdx.x >> 6;
#pragma unroll
  for (int i = 0; i < N; i++) {
    float x = v[i];
#pragma unroll
    for (int off = 1; off < 64; off <<= 1) x = fmaxf(x, __shfl_xor(x, off));
    if (lane == 0) scratch[wid * N + i] = x;
  }
  __syncthreads();
#pragma unroll
  for (int i = 0; i < N; i++)
    v[i] = fmaxf(fmaxf(scratch[i], scratch[N + i]),
                 fmaxf(scratch[2 * N + i], scratch[3 * N + i]));
  __syncthreads();
}

// ---------------- transpose+cast body: fp32 [K][N] -> bf16 [N][K], one 32x32 tile ----------------
__device__ __forceinline__ void transcast_body(
    const float* __restrict__ in, int ldin, u16t* __restrict__ out, int ldout,
    int nbi, int kbi, float (*tile)[33]) {
  int tx = threadIdx.x & 31, ty = threadIdx.x >> 5;
  int nb = nbi * 32, kb = kbi * 32;
#pragma unroll
  for (int r = 0; r < 4; r++)
    tile[ty + r * 8][tx] = in[(i64)(kb + ty + r * 8) * ldin + nb + tx];
  __syncthreads();
#pragma unroll
  for (int r = 0; r < 4; r++)
    out[(i64)(nb + ty + r * 8) * ldout + kb + tx] = f2bf(tile[tx][ty + r * 8]);
}

// ---------------- prep (step 1): ONLY WqkvT + xbf.  W1hT/W1bT/WoT live inside
// vb's region [17825792,18874368) and must NOT be written until vb dies after
// phaseA (r7/r8 NaN bug). ----------------
__global__ __launch_bounds__(256) void prep_kernel(
    const float* __restrict__ Wq, const float* __restrict__ Wk, const float* __restrict__ Wv,
    const float* __restrict__ x,
    u16t* __restrict__ WqkvT, u16t* __restrict__ xbf) {
  __shared__ float tile[32][33];
  int blk = blockIdx.x, t = threadIdx.x;
  if (blk < 3072) {
    int m = blk >> 10, bi = blk & 1023;
    const float* in = m == 0 ? Wq : m == 1 ? Wk : Wv;
    transcast_body(in, 1024, WqkvT + (i64)m * 1024 * 1024, 1024, bi & 31, bi >> 5, tile);
  } else {
    i64 e = ((i64)(blk - 3072) * 256 + t) * 4;
    float4 v = *(const float4*)(x + e);
    uint2 o;
    o.x = pk2(f2bf(v.x), f2bf(v.y));
    o.y = pk2(f2bf(v.z), f2bf(v.w));
    *(uint2*)(xbf + e) = o;
  }
}

// ---------------- bf16 MFMA GEMM body: A[M][K], B[N][K] -> C[M][N] fp32 ----------------
__device__ __forceinline__ void gemm_bt_body(
    const u16t* __restrict__ A, const u16t* __restrict__ B,
    float* __restrict__ C, int K, int ldc, int n0, int m0,
    u16t* As, u16t* Bs) {
  int t = threadIdx.x;
  int w = t >> 6, lane = t & 63;
  int l15 = lane & 15, quad = lane >> 4;
  int wm = (w & 1) * 64, wn = (w >> 1) * 64;
  f32x4 acc[4][4] = {};
  int srow = t >> 1, shalf = (t & 1) * 16;
  const u16t* Ag = A + (i64)(m0 + srow) * K + shalf;
  const u16t* Bg = B + (i64)(n0 + srow) * K + shalf;
  for (int k0 = 0; k0 < K; k0 += 32) {
    *(uint4*)&As[srow * 40 + shalf] = *(const uint4*)(Ag + k0);
    *(uint4*)&As[srow * 40 + shalf + 8] = *(const uint4*)(Ag + k0 + 8);
    *(uint4*)&Bs[srow * 40 + shalf] = *(const uint4*)(Bg + k0);
    *(uint4*)&Bs[srow * 40 + shalf + 8] = *(const uint4*)(Bg + k0 + 8);
    __syncthreads();
    short8 a[4], b[4];
#pragma unroll
    for (int mt = 0; mt < 4; mt++)
      a[mt] = *(const short8*)&As[(wm + mt * 16 + l15) * 40 + quad * 8];
#pragma unroll
    for (int nt = 0; nt < 4; nt++)
      b[nt] = *(const short8*)&Bs[(wn + nt * 16 + l15) * 40 + quad * 8];
#pragma unroll
    for (int mt = 0; mt < 4; mt++)
#pragma unroll
      for (int nt = 0; nt < 4; nt++)
        acc[mt][nt] = MFMA_BF16(a[mt], b[nt], acc[mt][nt]);
    __syncthreads();
  }
#pragma unroll
  for (int mt = 0; mt < 4; mt++) {
    int r0 = m0 + wm + mt * 16 + quad * 4;
#pragma unroll
    for (int nt = 0; nt < 4; nt++) {
      int cc = n0 + wn + nt * 16 + l15;
#pragma unroll
      for (int rg = 0; rg < 4; rg++)
        C[(i64)(r0 + rg) * ldc + cc] = acc[mt][nt][rg];
    }
  }
}

__global__ __launch_bounds__(256) void gemm_bt_kernel(
    const u16t* __restrict__ A, const u16t* __restrict__ B,
    float* __restrict__ C, int K, int ldc) {
  __shared__ u16t As[128 * 40];
  __shared__ u16t Bs[128 * 40];
  gemm_bt_body(A, B, C, K, ldc, blockIdx.x * 128, blockIdx.y * 128, As, Bs);
}

// ---------------- fused causal depthwise conv (K=4) + silu for q,k,v ----------------
__global__ __launch_bounds__(256) void conv_silu3_kernel(
    const float* __restrict__ pre, const float* __restrict__ qw,
    const float* __restrict__ kw, const float* __restrict__ vw,
    float* __restrict__ qo, float* __restrict__ ko, float* __restrict__ vo,
    u16t* __restrict__ brcat) {
  int seg = blockIdx.x >> 13;
  int idx = (blockIdx.x & 8191) * 256 + threadIdx.x;
  int c = idx & 1023, row = idx >> 10, l = row & 1023;
  const float* w = seg == 0 ? qw : seg == 1 ? kw : vw;
  float* out = seg == 0 ? qo : seg == 1 ? ko : vo;
  float4 wv = *(const float4*)(w + c * 4);
  const float* base = pre + (i64)row * 3072 + (seg << 10) + c;
  float acc = wv.w * base[0];
  if (l >= 1) acc += wv.z * base[-3072];
  if (l >= 2) acc += wv.y * base[-2 * 3072];
  if (l >= 3) acc += wv.x * base[-3 * 3072];
  float r = acc * sigmoidf_(acc);
  out[(i64)row * 1024 + c] = r;
  if (seg == 2)
    brcat[((i64)row * 4 + (c >> 8)) * 1024 + 768 + (c & 255)] = f2bf(r);
}

// ---------------- beta = sigmoid(x @ Wb) ----------------
__global__ __launch_bounds__(256) void beta_kernel(
    const float* __restrict__ x, const float* __restrict__ Wb, float* __restrict__ beta) {
  int row = blockIdx.x, t = threadIdx.x;
  __shared__ float sc[16];
  float a[4] = {0, 0, 0, 0};
  for (int c = t; c < 1024; c += 256) {
    float xv = x[(i64)row * 1024 + c];
    float4 wv = *(const float4*)(Wb + c * 4);
    a[0] += xv * wv.x; a[1] += xv * wv.y; a[2] += xv * wv.z; a[3] += xv * wv.w;
  }
  block_reduce_sum<4>(a, sc);
  if (t == 0) {
#pragma unroll
    for (int g = 0; g < 4; g++) beta[row * 4 + g] = sigmoidf_(a[g]);
  }
}

// ---------------- l2norm(q,k), v*beta, kn*beta; qn bf16 in delta layout ----------------
__global__ __launch_bounds__(256) void preprocess_kernel(
    const float* __restrict__ q, const float* __restrict__ k, const float* __restrict__ v,
    const float* __restrict__ beta, float* __restrict__ qn, float* __restrict__ kn,
    float* __restrict__ vb, float* __restrict__ kb, u16t* __restrict__ qnbf) {
  int row = blockIdx.x, t = threadIdx.x;   // row = (b*1024+l)*4+h
  __shared__ float sc[8];
  i64 base = (i64)row * 256 + t;
  float qv = q[base], kv = k[base], vv = v[base];
  float vals[2] = {qv * qv, kv * kv};
  block_reduce_sum<2>(vals, sc);
  float qi = rsqrtf(vals[0] + 1e-6f), ki = rsqrtf(vals[1] + 1e-6f);
  float bet = beta[row];
  float qnv = qv * qi, knv = kv * ki;
  qn[base] = qnv;
  kn[base] = knv;
  vb[base] = vv * bet;
  kb[base] = knv * bet;
  int b = row >> 12, l = (row >> 2) & 1023, h = row & 3;
  qnbf[((i64)(b * 4 + h) * 1024 + l) * 256 + t] = f2bf(qnv);
}

// ---------------- phase A: per-chunk UT-transform ----------------
__global__ __launch_bounds__(256) void phaseA_kernel(
    const float* __restrict__ qn, const float* __restrict__ kn,
    const float* __restrict__ vb, const float* __restrict__ kb,
    float* __restrict__ u_g, u16t* __restrict__ w_bf, u16t* __restrict__ attn_bf,
    u16t* __restrict__ knT) {
  __shared__ float KN[32][260];
  __shared__ float Ms[32][32];
  int blk = blockIdx.x, t = threadIdx.x;
  int i = blk & 31, bh = blk >> 5;
  int rbase = ((bh >> 2) * LL + i * 32) * NH + (bh & 3);
  i64 bhn = blk;
#pragma unroll
  for (int ii = 0; ii < 8; ii++) {
    int fid = t + ii * 256;
    int c = fid >> 6, dq = (fid & 63) << 2;
    *(float4*)&KN[c][dq] = *(const float4*)(kn + (i64)(rbase + c * NH) * 256 + dq);
  }
  __syncthreads();
  int c = t >> 3, e0 = (t & 7) * 4;
  const float* kbp = kb + (i64)(rbase + c * NH) * 256;
  const float* qp = qn + (i64)(rbase + c * NH) * 256;
  float am[4] = {0, 0, 0, 0}, aa[4] = {0, 0, 0, 0};
  for (int d = 0; d < 256; d += 4) {
    float4 kv = *(const float4*)(kbp + d);
    float4 qv = *(const float4*)(qp + d);
#pragma unroll
    for (int z = 0; z < 4; z++) {
      float4 nv = *(const float4*)&KN[e0 + z][d];
      am[z] += kv.x * nv.x + kv.y * nv.y + kv.z * nv.z + kv.w * nv.w;
      aa[z] += qv.x * nv.x + qv.y * nv.y + qv.z * nv.z + qv.w * nv.w;
    }
  }
  {
    uint2 o;
    u16t a0 = (e0 + 0 <= c) ? f2bf(aa[0]) : 0;
    u16t a1 = (e0 + 1 <= c) ? f2bf(aa[1]) : 0;
    u16t a2 = (e0 + 2 <= c) ? f2bf(aa[2]) : 0;
    u16t a3 = (e0 + 3 <= c) ? f2bf(aa[3]) : 0;
    o.x = pk2(a0, a1); o.y = pk2(a2, a3);
    *(uint2*)(attn_bf + bhn * 1024 + c * 32 + e0) = o;
  }
#pragma unroll
  for (int z = 0; z < 4; z++) {
    int e = e0 + z;
    Ms[c][e] = (e < c) ? am[z] : 0.0f;
  }
  __syncthreads();
  float uc[32], wc[32];
#pragma unroll
  for (int cc = 0; cc < 32; cc++) {
    float uval = vb[(i64)(rbase + cc * NH) * 256 + t];
    float wval = kb[(i64)(rbase + cc * NH) * 256 + t];
#pragma unroll
    for (int c2 = 0; c2 < cc; c2++) {
      float m = Ms[cc][c2];
      uval -= m * uc[c2];
      wval -= m * wc[c2];
    }
    uc[cc] = uval; wc[cc] = wval;
    u_g[(bhn * 32 + cc) * 256 + t] = uval;
    w_bf[(bhn * 32 + cc) * 256 + t] = f2bf(-wval);
  }
  int d = t;
  u16t o[32];
#pragma unroll
  for (int cc = 0; cc < 32; cc++) o[cc] = f2bf(KN[cc][d]);
#pragma unroll
  for (int z = 0; z < 4; z++) {
    uint4 vv;
    vv.x = pk2(o[z * 8 + 0], o[z * 8 + 1]);
    vv.y = pk2(o[z * 8 + 2], o[z * 8 + 3]);
    vv.z = pk2(o[z * 8 + 4], o[z * 8 + 5]);
    vv.w = pk2(o[z * 8 + 6], o[z * 8 + 7]);
    *(uint4*)(knT + (bhn * 256 + d) * 32 + z * 8) = vv;
  }
}

// ---------------- delta scan body ----------------
#define SROW 264
struct ScanBuf {
  short8 m8[8];
  f32x4 uc4;
  short8 af;
  short8 kf[4];
};

__device__ void delta_scan_body(
    int blk,
    const u16t* __restrict__ wbf, const u16t* __restrict__ knT,
    const float* __restrict__ u_g, const u16t* __restrict__ qnbf,
    const u16t* __restrict__ attnbf,
    float* __restrict__ dlt, u16t* __restrict__ brcat,
    u16t* Sbf, u16t* Ubf) {
  int t = threadIdx.x, w = t >> 6, lane = t & 63;
  int l15 = lane & 15, quad = lane >> 4;
  int bh = blk & 7, jb = blk >> 3, j0 = jb * 16;
  int b_ = bh >> 2, h_ = bh & 3;
  bool isU = (w < 2);
  int wc = isU ? w : (w - 2);
  for (int idx = t; idx < 16 * SROW; idx += 256) Sbf[idx] = 0;
  f32x4 accS[4] = {};
  __syncthreads();
  __builtin_amdgcn_s_setprio(1);

  auto load_chunk = [&](int i, ScanBuf& B) {
    i64 bhn = (i64)bh * 32 + i;
    const u16t* mbase = isU
        ? wbf + (bhn * 32 + wc * 16 + l15) * 256 + quad * 8
        : qnbf + ((i64)bh * 1024 + i * 32 + wc * 16 + l15) * 256 + quad * 8;
#pragma unroll
    for (int kd = 0; kd < 8; kd++) B.m8[kd] = *(const short8*)(mbase + kd * 32);
    if (isU) {
      int cm = wc * 16 + quad * 4;
#pragma unroll
      for (int r = 0; r < 4; r++)
        B.uc4[r] = u_g[(bhn * 32 + cm + r) * 256 + j0 + l15];
    } else {
      B.af = *(const short8*)(attnbf + bhn * 1024 + (wc * 16 + l15) * 32 + quad * 8);
    }
#pragma unroll
    for (int dt = 0; dt < 4; dt++)
      B.kf[dt] = *(const short8*)(knT + (bhn * 256 + w * 64 + dt * 16 + l15) * 32 + quad * 8);
  };

  auto process = [&](int i, ScanBuf& B) {
    f32x4 zero = {};
    f32x4 ca = isU ? B.uc4 : zero;
    f32x4 cb = zero;
#pragma unroll
    for (int kd = 0; kd < 4; kd++) {
      short8 sfa = *(const short8*)&Sbf[l15 * SROW + kd * 32 + quad * 8];
      short8 sfb = *(const short8*)&Sbf[l15 * SROW + (kd + 4) * 32 + quad * 8];
      ca = MFMA_BF16(B.m8[kd], sfa, ca);
      cb = MFMA_BF16(B.m8[kd + 4], sfb, cb);
    }
    f32x4 cacc;
#pragma unroll
    for (int r = 0; r < 4; r++) cacc[r] = ca[r] + cb[r];
    if (isU) {
      int cm = wc * 16 + quad * 4;
      uint2 o;
      o.x = cvt_pk_bf16(cacc[0], cacc[1]);
      o.y = cvt_pk_bf16(cacc[2], cacc[3]);
      *(uint2*)&Ubf[l15 * 40 + cm] = o;
    }
    barrier_lds_only();
    short8 bu = *(const short8*)&Ubf[l15 * 40 + quad * 8];
    if (!isU) {
      cacc = MFMA_BF16(B.af, bu, cacc);
#pragma unroll
      for (int rg = 0; rg < 4; rg++) {
        int l = i * 32 + wc * 16 + quad * 4 + rg;
        i64 row = ((i64)b_ * 1024 + l) * 4 + h_;
        dlt[row * 256 + j0 + l15] = cacc[rg];
        brcat[row * 1024 + 512 + j0 + l15] = f2bf(cacc[rg]);
      }
    }
#pragma unroll
    for (int dt = 0; dt < 4; dt++) accS[dt] = MFMA_BF16(B.kf[dt], bu, accS[dt]);
#pragma unroll
    for (int dt = 0; dt < 4; dt++) {
      uint2 o;
      o.x = cvt_pk_bf16(accS[dt][0], accS[dt][1]);
      o.y = cvt_pk_bf16(accS[dt][2], accS[dt][3]);
      *(uint2*)&Sbf[l15 * SROW + w * 64 + dt * 16 + quad * 4] = o;
    }
    barrier_lds_only();
  };

  ScanBuf b0, b1;
  load_chunk(0, b0);
#pragma unroll 1
  for (int ii = 0; ii < 16; ii++) {
    int i = ii * 2;
    load_chunk(i + 1, b1);
    process(i, b0);
    if (ii < 15) load_chunk(i + 2, b0);
    process(i + 1, b1);
  }
  __builtin_amdgcn_s_setprio(0);
}

// ---------------- scan: standalone dispatch (dedicated rocprof row) ----------------
__global__ __launch_bounds__(256) void scan_kernel(
    const u16t* __restrict__ wbf, const u16t* __restrict__ knT,
    const float* __restrict__ u_g, const u16t* __restrict__ qnbf,
    const u16t* __restrict__ attnbf,
    float* __restrict__ dlt, u16t* __restrict__ brcat) {
  __shared__ __attribute__((aligned(16))) u16t Sbf[16 * SROW];
  __shared__ __attribute__((aligned(16))) u16t Ubf[16 * 40];
  delta_scan_body(blockIdx.x, wbf, knT, u_g, qnbf, attnbf, dlt, brcat, Sbf, Ubf);
}

// ---------------- FIR body ----------------
__device__ void fir2_body(
    int blk, const float* __restrict__ v,
    const float* __restrict__ f_s, const float* __restrict__ f_l,
    float* __restrict__ fs, float* __restrict__ fl, u16t* __restrict__ brcat) {
  int t = threadIdx.x;
  int b = blk >> 8, h = (blk >> 6) & 3, lc = blk & 63;
  int l0 = lc * 16;
  float flw[31], fsw[3];
  const float* flp = f_l + ((i64)h * 256 + t) * 31;
#pragma unroll
  for (int j = 0; j < 31; j++) flw[j] = flp[j];
  const float* fsp = f_s + ((i64)h * 256 + t) * 3;
#pragma unroll
  for (int j = 0; j < 3; j++) fsw[j] = fsp[j];
  float win[46];
#pragma unroll
  for (int r = 0; r < 46; r++) {
    int l = l0 - 30 + r;
    win[r] = (l >= 0) ? v[(((i64)b * 1024 + l) * 4 + h) * 256 + t] : 0.0f;
  }
#pragma unroll
  for (int i = 0; i < 16; i++) {
    float al = 0.0f;
#pragma unroll
    for (int j = 0; j < 31; j++) al += flw[j] * win[i + j];
    float as = fsw[0] * win[i + 28] + fsw[1] * win[i + 29] + fsw[2] * win[i + 30];
    i64 row = ((i64)b * 1024 + (l0 + i)) * 4 + h;
    fs[row * 256 + t] = as;
    fl[row * 256 + t] = al;
    brcat[row * 1024 + t] = f2bf(as);
    brcat[row * 1024 + 256 + t] = f2bf(al);
  }
}

// ---------------- firprep: fir(512) + W1/Wo transposes(2048) + wsum(24) ----------------
// (prep2 folded in; all after phaseA so the vb-aliased W1hT/W1bT/WoT are safe)
__global__ __launch_bounds__(256) void firprep_kernel(
    const float* __restrict__ vbuf, const float* __restrict__ firs,
    const float* __restrict__ firl, float* __restrict__ fs, float* __restrict__ fl,
    u16t* __restrict__ brcat,
    const float* __restrict__ gW1, const float* __restrict__ Wo,
    u16t* __restrict__ W1hT, u16t* __restrict__ W1bT, u16t* __restrict__ WoT,
    float* __restrict__ wsum) {
  __shared__ float tile[32][33];
  int blk = blockIdx.x;
  if (blk < 512) {
    fir2_body(blk, vbuf, firs, firl, fs, fl, brcat);
  } else if (blk < 2560) {
    int pb = blk - 512;
    if (pb < 1024) {
      int which = pb >> 9, bi = pb & 511;
      const float* in = gW1 + (which ? (i64)4096 * 512 : 0);
      transcast_body(in, 512, which ? W1bT : W1hT, 1024, bi & 15, bi >> 4, tile);
    } else {
      int bi = pb - 1024;
      transcast_body(Wo, 1024, WoT, 1024, bi & 31, bi >> 5, tile);
    }
  } else {
    int bi = blk - 2560;         // 24 blocks: 12 stats x 2 col-halves
    int s12 = bi >> 1, col = (bi & 1) * 256 + threadIdx.x;
    const float* p = gW1 + (i64)(1024 + s12 * 256) * 512 + col;
    float acc = 0.0f;
    for (int r = 0; r < 256; r++) acc += p[(i64)r * 512];
    wsum[s12 * 512 + col] = acc;
  }
}

// ---------------- gemm2: hbase gemm(64) + branchW gemm(256) ----------------
__global__ __launch_bounds__(256) void gemm2_kernel(
    const u16t* __restrict__ xbf, const u16t* __restrict__ W1hT,
    float* __restrict__ hbase,
    const u16t* __restrict__ brcat, const u16t* __restrict__ W1bT,
    float* __restrict__ branchW) {
  __shared__ u16t As[128 * 40];
  __shared__ u16t Bs[128 * 40];
  int blk = blockIdx.x;
  if (blk < 64) {
    gemm_bt_body(xbf, W1hT, hbase, 1024, 512, (blk & 3) * 128, (blk >> 2) * 128, As, Bs);
  } else {
    int bi = blk - 64;
    gemm_bt_body(brcat, W1bT, branchW, 1024, 512, (bi & 3) * 128, (bi >> 2) * 128, As, Bs);
  }
}

// ---------------- fused gate MLP tail + mix + RMS norm (stats computed inline) ----------------
__global__ __launch_bounds__(256) void gatemix_kernel(
    const float* __restrict__ hbase, const float* __restrict__ brW,
    const float* __restrict__ wsum,
    const float* __restrict__ gb1, const float* __restrict__ gW2,
    const float* __restrict__ gb2, const float* __restrict__ temp,
    const float* __restrict__ epsf,
    const float* __restrict__ fs, const float* __restrict__ fl,
    const float* __restrict__ dlt, const float* __restrict__ v,
    const float* __restrict__ onw, u16t* __restrict__ out) {
  int row = blockIdx.x, t = threadIdx.x;
  int bl = row >> 2, h = row & 3;
  __shared__ float sc[32];
  __shared__ float gwsh[4];
  // ---- load branch values once; reused for stats AND the final mix ----
  i64 base = (i64)row * 256 + t;
  float bfs = fs[base], bfl = fl[base], bdl = dlt[base], bv = v[base];
  // ---- inline stats: one batched sum/sumsq reduce + one batched max reduce ----
  float sums[8] = {bfs, bfs * bfs, bfl, bfl * bfl, bdl, bdl * bdl, bv, bv * bv};
  block_reduce_sum<8>(sums, sc);
  float mx4[4] = {bfs, bfl, bdl, bv};
  block_reduce_max<4>(mx4, sc);
  float st[12];
#pragma unroll
  for (int p = 0; p < 4; p++) {
    st[p * 3 + 0] = sums[p * 2] * (1.0f / 256.0f);
    st[p * 3 + 1] = sqrtf(fmaxf(sums[p * 2 + 1] * (1.0f / 256.0f), 1e-8f));
    st[p * 3 + 2] = mx4[p];
  }
  float lg[4] = {0, 0, 0, 0};
#pragma unroll
  for (int jj = 0; jj < 2; jj++) {
    int o = jj * 256 + t;
    float hm = hbase[(i64)bl * 512 + o] + brW[(i64)row * 512 + o] + gb1[o];
#pragma unroll
    for (int s = 0; s < 12; s++) hm += st[s] * wsum[s * 512 + o];
    float ge = 0.5f * hm * (1.0f + erff(hm * 0.70710678118654752f));
    float4 w2 = *(const float4*)(gW2 + o * 4);
    lg[0] += ge * w2.x; lg[1] += ge * w2.y; lg[2] += ge * w2.z; lg[3] += ge * w2.w;
  }
  block_reduce_sum<4>(lg, sc);
  if (t == 0) {
    float tt = fminf(fmaxf(temp[h], 0.2f), 10.0f);
    float l0 = (lg[0] + gb2[0]) / tt;
    float l1 = (lg[1] + gb2[1]) / tt;
    float l2 = (lg[2] + gb2[2]) / tt;
    float l3 = (lg[3] + gb2[3]) / tt;
    float m = fmaxf(fmaxf(l0, l1), fmaxf(l2, l3));
    float e0 = expf(l0 - m), e1 = expf(l1 - m), e2 = expf(l2 - m), e3 = expf(l3 - m);
    float ssum = e0 + e1 + e2 + e3;
    float w0 = e0 / ssum, w1 = e1 / ssum, w2 = e2 / ssum, w3 = e3 / ssum;
    w0 = fmaxf(w0, fminf(fmaxf(epsf[h * 4 + 0], 1e-7f), 0.1f));
    w1 = fmaxf(w1, fminf(fmaxf(epsf[h * 4 + 1], 1e-7f), 0.1f));
    w2 = fmaxf(w2, fminf(fmaxf(epsf[h * 4 + 2], 1e-7f), 0.1f));
    w3 = fmaxf(w3, fminf(fmaxf(epsf[h * 4 + 3], 1e-7f), 0.1f));
    float s2 = w0 + w1 + w2 + w3;
    gwsh[0] = w0 / s2; gwsh[1] = w1 / s2; gwsh[2] = w2 / s2; gwsh[3] = w3 / s2;
  }
  __syncthreads();
  float g0 = gwsh[0], g1 = gwsh[1], g2 = gwsh[2], g3 = gwsh[3];
  float o = g0 * bfs + g1 * bfl + g2 * bdl + g3 * bv;
  float vals[1] = {o * o};
  block_reduce_sum<1>(vals, sc);
  float scale = rsqrtf(vals[0] * (1.0f / 256.0f) + 1e-5f);
  out[(i64)bl * 1024 + h * 256 + t] = f2bf(o * scale * onw[t]);
}

extern "C" void kernel_launch(void* const* d_in, const int* in_sizes, int n_in,
                              void* d_out, int out_size, void* d_ws, size_t ws_size,
                              hipStream_t stream) {
  (void)in_sizes; (void)n_in; (void)out_size; (void)ws_size;
  const float* x    = (const float*)d_in[0];
  const float* Wq   = (const float*)d_in[1];
  const float* Wk   = (const float*)d_in[2];
  const float* Wv   = (const float*)d_in[3];
  const float* Wb   = (const float*)d_in[4];
  const float* qcw  = (const float*)d_in[5];
  const float* kcw  = (const float*)d_in[6];
  const float* vcw  = (const float*)d_in[7];
  const float* gW1  = (const float*)d_in[8];
  const float* gb1  = (const float*)d_in[9];
  const float* gW2  = (const float*)d_in[10];
  const float* gb2  = (const float*)d_in[11];
  const float* temp = (const float*)d_in[12];
  const float* epsf = (const float*)d_in[13];
  const float* onw  = (const float*)d_in[14];
  const float* Wo   = (const float*)d_in[15];
  const float* firs = (const float*)d_in[16];
  const float* firl = (const float*)d_in[17];
  float* out = (float*)d_out;

  float* ws = (float*)d_ws;
  // ---- workspace map (float offsets); W1hT/W1bT/WoT share vb's region and
  // are only written AFTER phaseA (firprep) — r7/r8 NaN bug fix ----
  float* qkv_pre  = ws + 0;                       // 2048*3072 fp32 (dead after conv)
  float* branchW  = ws + 0;                       // 8192*512 fp32 (gemm2+)
  float* hbase    = ws + 4194304;                 // 2048*512 fp32 (gemm2+)
  u16t*  brcat    = (u16t*)(ws + 6291456);        // 8192*1024 bf16
  float* qbuf     = ws + 10485760; float* qn = qbuf;
  float* kbuf     = ws + 12582912; float* kn = kbuf;
  float* vbuf     = ws + 14680064;
  float* vb       = ws + 16777216;                // dead after phaseA
  u16t*  omix_bf  = (u16t*)(ws + 16777216);       // gatemix+
  u16t*  W1hT     = (u16t*)(ws + 17825792);       // firprep+ (inside dead vb)
  u16t*  W1bT     = (u16t*)(ws + 18087936);
  u16t*  WoT      = (u16t*)(ws + 18350080);
  float* kb       = ws + 18874368;                // dead after phaseA
  float* dlt      = ws + 18874368;                // scan output
  float* u_g      = ws + 20971520;
  u16t*  w_bf     = (u16t*)(ws + 23068672);
  u16t*  qn_bf    = (u16t*)(ws + 24117248);
  u16t*  knT      = (u16t*)(ws + 25165824);
  u16t*  attn_bf  = (u16t*)(ws + 26214400);
  float* fs       = ws + 26345472;
  float* fl       = ws + 28442624;
  u16t*  xbf      = (u16t*)(ws + 30539776);
  u16t*  WqkvT    = (u16t*)(ws + 31588352);
  float* betab    = ws + 33161216;                // 8192 fp32
  float* wsum     = ws + 33267712;

  // 1) prep: QKV weight transpose + x cast
  prep_kernel<<<5120, 256, 0, stream>>>(Wq, Wk, Wv, x, WqkvT, xbf);
  // 2) QKV GEMM
  gemm_bt_kernel<<<dim3(24, 16), 256, 0, stream>>>(xbf, WqkvT, qkv_pre, 1024, 3072);
  // 3) conv+silu (v also -> brcat col 768)
  conv_silu3_kernel<<<24576, 256, 0, stream>>>(qkv_pre, qcw, kcw, vcw, qbuf, kbuf, vbuf, brcat);
  // 4) beta + preprocess
  beta_kernel<<<2048, 256, 0, stream>>>(x, Wb, betab);
  preprocess_kernel<<<8192, 256, 0, stream>>>(qbuf, kbuf, vbuf, betab, qn, kn, vb, kb, qn_bf);
  // 5) phase A (last reader of vb/kb)
  phaseA_kernel<<<256, 256, 0, stream>>>(qn, kn, vb, kb, u_g, w_bf, attn_bf, knT);
  // 6) firprep: FIR + W1/Wo transposes (into dead vb region) + wsum
  firprep_kernel<<<2584, 256, 0, stream>>>(vbuf, firs, firl, fs, fl, brcat,
                                           gW1, Wo, W1hT, W1bT, WoT, wsum);
  // 7) scan (standalone dispatch — clean profile)
  scan_kernel<<<128, 256, 0, stream>>>(w_bf, knT, u_g, qn_bf, attn_bf, dlt, brcat);
  // 8) gemm2: hbase GEMM + branchW GEMM
  gemm2_kernel<<<320, 256, 0, stream>>>(xbf, W1hT, hbase, brcat, W1bT, branchW);
  // 9) gate tail + mix + RMS (emits omix_bf)
  gatemix_kernel<<<8192, 256, 0, stream>>>(hbase, branchW, wsum, gb1, gW2, gb2,
                                           temp, epsf, fs, fl, dlt, vbuf, onw, omix_bf);
  // 10) final projection
  gemm_bt_kernel<<<dim3(8, 16), 256, 0, stream>>>(omix_bf, WoT, out, 1024, 1024);
}

// Round 4
// 339.478 us; speedup vs baseline: 1.1392x; 1.1392x over previous
//
#include <hip/hip_runtime.h>
#include <math.h>

// Problem constants
#define BB 2
#define LL 1024
#define HIDD 1024
#define NH 4
#define DD 256
#define NCH 32
#define ROWS 2048
#define HROWS 8192

typedef long long i64;
typedef unsigned short u16t;
typedef unsigned int u32t;
typedef __attribute__((ext_vector_type(8))) short short8;
typedef __attribute__((ext_vector_type(4))) float f32x4;
#define MFMA_BF16(a, b, c) __builtin_amdgcn_mfma_f32_16x16x32_bf16(a, b, c, 0, 0, 0)

__device__ __forceinline__ float sigmoidf_(float x) { return 1.0f / (1.0f + expf(-x)); }

__device__ __forceinline__ u16t f2bf(float f) {
  u32t u = __float_as_uint(f);
  u = u + 0x7FFFu + ((u >> 16) & 1u);
  return (u16t)(u >> 16);
}
__device__ __forceinline__ u32t pk2(u16t a, u16t b) { return (u32t)a | ((u32t)b << 16); }

// HW packed f32->bf16 RNE convert (gfx950): 1 instr vs 6-op bit-trick pair.
__device__ __forceinline__ u32t cvt_pk_bf16(float lo, float hi) {
  u32t r;
  asm("v_cvt_pk_bf16_f32 %0, %1, %2" : "=v"(r) : "v"(lo), "v"(hi));
  return r;
}

// counted-wait barrier: drain only LDS ops, keep global loads in flight.
__device__ __forceinline__ void barrier_lds_only() {
  asm volatile("s_waitcnt lgkmcnt(0)" ::: "memory");
  __builtin_amdgcn_s_barrier();
  asm volatile("" ::: "memory");
}

// ---------------- block reduction helpers (blockDim == 256) ----------------
template<int N>
__device__ __forceinline__ void block_reduce_sum(float* v, float* scratch) {
  int lane = threadIdx.x & 63, wid = threadIdx.x >> 6;
#pragma unroll
  for (int i = 0; i < N; i++) {
    float x = v[i];
#pragma unroll
    for (int off = 1; off < 64; off <<= 1) x += __shfl_xor(x, off);
    if (lane == 0) scratch[wid * N + i] = x;
  }
  __syncthreads();
#pragma unroll
  for (int i = 0; i < N; i++)
    v[i] = scratch[i] + scratch[N + i] + scratch[2 * N + i] + scratch[3 * N + i];
  __syncthreads();
}

// ---------------- transpose+cast body: fp32 [K][N] -> bf16 [N][K], one 32x32 tile ----------------
__device__ __forceinline__ void transcast_body(
    const float* __restrict__ in, int ldin, u16t* __restrict__ out, int ldout,
    int nbi, int kbi, float (*tile)[33]) {
  int tx = threadIdx.x & 31, ty = threadIdx.x >> 5;
  int nb = nbi * 32, kb = kbi * 32;
#pragma unroll
  for (int r = 0; r < 4; r++)
    tile[ty + r * 8][tx] = in[(i64)(kb + ty + r * 8) * ldin + nb + tx];
  __syncthreads();
#pragma unroll
  for (int r = 0; r < 4; r++)
    out[(i64)(nb + ty + r * 8) * ldout + kb + tx] = f2bf(tile[tx][ty + r * 8]);
}

// ---------------- prep (step 1): ONLY WqkvT + xbf.  W1hT/W1bT/WoT live inside
// vb's region and must NOT be written until vb dies after phaseA. ----------------
__global__ __launch_bounds__(256) void prep_kernel(
    const float* __restrict__ Wq, const float* __restrict__ Wk, const float* __restrict__ Wv,
    const float* __restrict__ x,
    u16t* __restrict__ WqkvT, u16t* __restrict__ xbf) {
  __shared__ float tile[32][33];
  int blk = blockIdx.x, t = threadIdx.x;
  if (blk < 3072) {
    int m = blk >> 10, bi = blk & 1023;
    const float* in = m == 0 ? Wq : m == 1 ? Wk : Wv;
    transcast_body(in, 1024, WqkvT + (i64)m * 1024 * 1024, 1024, bi & 31, bi >> 5, tile);
  } else {
    i64 e = ((i64)(blk - 3072) * 256 + t) * 4;
    float4 v = *(const float4*)(x + e);
    uint2 o;
    o.x = pk2(f2bf(v.x), f2bf(v.y));
    o.y = pk2(f2bf(v.z), f2bf(v.w));
    *(uint2*)(xbf + e) = o;
  }
}

// ---------------- bf16 MFMA GEMM body: A[M][K], B[N][K] -> C[M][N] fp32 ----------------
__device__ __forceinline__ void gemm_bt_body(
    const u16t* __restrict__ A, const u16t* __restrict__ B,
    float* __restrict__ C, int K, int ldc, int n0, int m0,
    u16t* As, u16t* Bs) {
  int t = threadIdx.x;
  int w = t >> 6, lane = t & 63;
  int l15 = lane & 15, quad = lane >> 4;
  int wm = (w & 1) * 64, wn = (w >> 1) * 64;
  f32x4 acc[4][4] = {};
  int srow = t >> 1, shalf = (t & 1) * 16;
  const u16t* Ag = A + (i64)(m0 + srow) * K + shalf;
  const u16t* Bg = B + (i64)(n0 + srow) * K + shalf;
  for (int k0 = 0; k0 < K; k0 += 32) {
    *(uint4*)&As[srow * 40 + shalf] = *(const uint4*)(Ag + k0);
    *(uint4*)&As[srow * 40 + shalf + 8] = *(const uint4*)(Ag + k0 + 8);
    *(uint4*)&Bs[srow * 40 + shalf] = *(const uint4*)(Bg + k0);
    *(uint4*)&Bs[srow * 40 + shalf + 8] = *(const uint4*)(Bg + k0 + 8);
    __syncthreads();
    short8 a[4], b[4];
#pragma unroll
    for (int mt = 0; mt < 4; mt++)
      a[mt] = *(const short8*)&As[(wm + mt * 16 + l15) * 40 + quad * 8];
#pragma unroll
    for (int nt = 0; nt < 4; nt++)
      b[nt] = *(const short8*)&Bs[(wn + nt * 16 + l15) * 40 + quad * 8];
#pragma unroll
    for (int mt = 0; mt < 4; mt++)
#pragma unroll
      for (int nt = 0; nt < 4; nt++)
        acc[mt][nt] = MFMA_BF16(a[mt], b[nt], acc[mt][nt]);
    __syncthreads();
  }
#pragma unroll
  for (int mt = 0; mt < 4; mt++) {
    int r0 = m0 + wm + mt * 16 + quad * 4;
#pragma unroll
    for (int nt = 0; nt < 4; nt++) {
      int cc = n0 + wn + nt * 16 + l15;
#pragma unroll
      for (int rg = 0; rg < 4; rg++)
        C[(i64)(r0 + rg) * ldc + cc] = acc[mt][nt][rg];
    }
  }
}

__global__ __launch_bounds__(256) void gemm_bt_kernel(
    const u16t* __restrict__ A, const u16t* __restrict__ B,
    float* __restrict__ C, int K, int ldc) {
  __shared__ u16t As[128 * 40];
  __shared__ u16t Bs[128 * 40];
  gemm_bt_body(A, B, C, K, ldc, blockIdx.x * 128, blockIdx.y * 128, As, Bs);
}

// ---------------- fused causal depthwise conv (K=4) + silu for q,k,v ----------------
__global__ __launch_bounds__(256) void conv_silu3_kernel(
    const float* __restrict__ pre, const float* __restrict__ qw,
    const float* __restrict__ kw, const float* __restrict__ vw,
    float* __restrict__ qo, float* __restrict__ ko, float* __restrict__ vo,
    u16t* __restrict__ brcat) {
  int seg = blockIdx.x >> 13;
  int idx = (blockIdx.x & 8191) * 256 + threadIdx.x;
  int c = idx & 1023, row = idx >> 10, l = row & 1023;
  const float* w = seg == 0 ? qw : seg == 1 ? kw : vw;
  float* out = seg == 0 ? qo : seg == 1 ? ko : vo;
  float4 wv = *(const float4*)(w + c * 4);
  const float* base = pre + (i64)row * 3072 + (seg << 10) + c;
  float acc = wv.w * base[0];
  if (l >= 1) acc += wv.z * base[-3072];
  if (l >= 2) acc += wv.y * base[-2 * 3072];
  if (l >= 3) acc += wv.x * base[-3 * 3072];
  float r = acc * sigmoidf_(acc);
  out[(i64)row * 1024 + c] = r;
  if (seg == 2)
    brcat[((i64)row * 4 + (c >> 8)) * 1024 + 768 + (c & 255)] = f2bf(r);
}

// ---------------- beta = sigmoid(x @ Wb) ----------------
__global__ __launch_bounds__(256) void beta_kernel(
    const float* __restrict__ x, const float* __restrict__ Wb, float* __restrict__ beta) {
  int row = blockIdx.x, t = threadIdx.x;
  __shared__ float sc[16];
  float a[4] = {0, 0, 0, 0};
  for (int c = t; c < 1024; c += 256) {
    float xv = x[(i64)row * 1024 + c];
    float4 wv = *(const float4*)(Wb + c * 4);
    a[0] += xv * wv.x; a[1] += xv * wv.y; a[2] += xv * wv.z; a[3] += xv * wv.w;
  }
  block_reduce_sum<4>(a, sc);
  if (t == 0) {
#pragma unroll
    for (int g = 0; g < 4; g++) beta[row * 4 + g] = sigmoidf_(a[g]);
  }
}

// ---------------- l2norm(q,k), v*beta, kn*beta; qn bf16 in delta layout ----------------
__global__ __launch_bounds__(256) void preprocess_kernel(
    const float* __restrict__ q, const float* __restrict__ k, const float* __restrict__ v,
    const float* __restrict__ beta, float* __restrict__ qn, float* __restrict__ kn,
    float* __restrict__ vb, float* __restrict__ kb, u16t* __restrict__ qnbf) {
  int row = blockIdx.x, t = threadIdx.x;   // row = (b*1024+l)*4+h
  __shared__ float sc[8];
  i64 base = (i64)row * 256 + t;
  float qv = q[base], kv = k[base], vv = v[base];
  float vals[2] = {qv * qv, kv * kv};
  block_reduce_sum<2>(vals, sc);
  float qi = rsqrtf(vals[0] + 1e-6f), ki = rsqrtf(vals[1] + 1e-6f);
  float bet = beta[row];
  float qnv = qv * qi, knv = kv * ki;
  qn[base] = qnv;
  kn[base] = knv;
  vb[base] = vv * bet;
  kb[base] = knv * bet;
  int b = row >> 12, l = (row >> 2) & 1023, h = row & 3;
  qnbf[((i64)(b * 4 + h) * 1024 + l) * 256 + t] = f2bf(qnv);
}

// ---------------- phase A: per-chunk UT-transform ----------------
__global__ __launch_bounds__(256) void phaseA_kernel(
    const float* __restrict__ qn, const float* __restrict__ kn,
    const float* __restrict__ vb, const float* __restrict__ kb,
    float* __restrict__ u_g, u16t* __restrict__ w_bf, u16t* __restrict__ attn_bf,
    u16t* __restrict__ knT) {
  __shared__ float KN[32][260];
  __shared__ float Ms[32][32];
  int blk = blockIdx.x, t = threadIdx.x;
  int i = blk & 31, bh = blk >> 5;
  int rbase = ((bh >> 2) * LL + i * 32) * NH + (bh & 3);
  i64 bhn = blk;
#pragma unroll
  for (int ii = 0; ii < 8; ii++) {
    int fid = t + ii * 256;
    int c = fid >> 6, dq = (fid & 63) << 2;
    *(float4*)&KN[c][dq] = *(const float4*)(kn + (i64)(rbase + c * NH) * 256 + dq);
  }
  __syncthreads();
  int c = t >> 3, e0 = (t & 7) * 4;
  const float* kbp = kb + (i64)(rbase + c * NH) * 256;
  const float* qp = qn + (i64)(rbase + c * NH) * 256;
  float am[4] = {0, 0, 0, 0}, aa[4] = {0, 0, 0, 0};
  for (int d = 0; d < 256; d += 4) {
    float4 kv = *(const float4*)(kbp + d);
    float4 qv = *(const float4*)(qp + d);
#pragma unroll
    for (int z = 0; z < 4; z++) {
      float4 nv = *(const float4*)&KN[e0 + z][d];
      am[z] += kv.x * nv.x + kv.y * nv.y + kv.z * nv.z + kv.w * nv.w;
      aa[z] += qv.x * nv.x + qv.y * nv.y + qv.z * nv.z + qv.w * nv.w;
    }
  }
  {
    uint2 o;
    u16t a0 = (e0 + 0 <= c) ? f2bf(aa[0]) : 0;
    u16t a1 = (e0 + 1 <= c) ? f2bf(aa[1]) : 0;
    u16t a2 = (e0 + 2 <= c) ? f2bf(aa[2]) : 0;
    u16t a3 = (e0 + 3 <= c) ? f2bf(aa[3]) : 0;
    o.x = pk2(a0, a1); o.y = pk2(a2, a3);
    *(uint2*)(attn_bf + bhn * 1024 + c * 32 + e0) = o;
  }
#pragma unroll
  for (int z = 0; z < 4; z++) {
    int e = e0 + z;
    Ms[c][e] = (e < c) ? am[z] : 0.0f;
  }
  __syncthreads();
  float uc[32], wc[32];
#pragma unroll
  for (int cc = 0; cc < 32; cc++) {
    float uval = vb[(i64)(rbase + cc * NH) * 256 + t];
    float wval = kb[(i64)(rbase + cc * NH) * 256 + t];
#pragma unroll
    for (int c2 = 0; c2 < cc; c2++) {
      float m = Ms[cc][c2];
      uval -= m * uc[c2];
      wval -= m * wc[c2];
    }
    uc[cc] = uval; wc[cc] = wval;
    u_g[(bhn * 32 + cc) * 256 + t] = uval;
    w_bf[(bhn * 32 + cc) * 256 + t] = f2bf(-wval);
  }
  int d = t;
  u16t o[32];
#pragma unroll
  for (int cc = 0; cc < 32; cc++) o[cc] = f2bf(KN[cc][d]);
#pragma unroll
  for (int z = 0; z < 4; z++) {
    uint4 vv;
    vv.x = pk2(o[z * 8 + 0], o[z * 8 + 1]);
    vv.y = pk2(o[z * 8 + 2], o[z * 8 + 3]);
    vv.z = pk2(o[z * 8 + 4], o[z * 8 + 5]);
    vv.w = pk2(o[z * 8 + 6], o[z * 8 + 7]);
    *(uint4*)(knT + (bhn * 256 + d) * 32 + z * 8) = vv;
  }
}

// ---------------- delta scan body ----------------
#define SROW 264
struct ScanBuf {
  short8 m8[8];
  f32x4 uc4;
  short8 af;
  short8 kf[4];
};

__device__ void delta_scan_body(
    int blk,
    const u16t* __restrict__ wbf, const u16t* __restrict__ knT,
    const float* __restrict__ u_g, const u16t* __restrict__ qnbf,
    const u16t* __restrict__ attnbf,
    float* __restrict__ dlt, u16t* __restrict__ brcat,
    u16t* Sbf, u16t* Ubf) {
  int t = threadIdx.x, w = t >> 6, lane = t & 63;
  int l15 = lane & 15, quad = lane >> 4;
  int bh = blk & 7, jb = blk >> 3, j0 = jb * 16;
  int b_ = bh >> 2, h_ = bh & 3;
  bool isU = (w < 2);
  int wc = isU ? w : (w - 2);
  for (int idx = t; idx < 16 * SROW; idx += 256) Sbf[idx] = 0;
  f32x4 accS[4] = {};
  __syncthreads();
  __builtin_amdgcn_s_setprio(1);

  auto load_chunk = [&](int i, ScanBuf& B) {
    i64 bhn = (i64)bh * 32 + i;
    const u16t* mbase = isU
        ? wbf + (bhn * 32 + wc * 16 + l15) * 256 + quad * 8
        : qnbf + ((i64)bh * 1024 + i * 32 + wc * 16 + l15) * 256 + quad * 8;
#pragma unroll
    for (int kd = 0; kd < 8; kd++) B.m8[kd] = *(const short8*)(mbase + kd * 32);
    if (isU) {
      int cm = wc * 16 + quad * 4;
#pragma unroll
      for (int r = 0; r < 4; r++)
        B.uc4[r] = u_g[(bhn * 32 + cm + r) * 256 + j0 + l15];
    } else {
      B.af = *(const short8*)(attnbf + bhn * 1024 + (wc * 16 + l15) * 32 + quad * 8);
    }
#pragma unroll
    for (int dt = 0; dt < 4; dt++)
      B.kf[dt] = *(const short8*)(knT + (bhn * 256 + w * 64 + dt * 16 + l15) * 32 + quad * 8);
  };

  auto process = [&](int i, ScanBuf& B) {
    f32x4 zero = {};
    f32x4 ca = isU ? B.uc4 : zero;
    f32x4 cb = zero;
#pragma unroll
    for (int kd = 0; kd < 4; kd++) {
      short8 sfa = *(const short8*)&Sbf[l15 * SROW + kd * 32 + quad * 8];
      short8 sfb = *(const short8*)&Sbf[l15 * SROW + (kd + 4) * 32 + quad * 8];
      ca = MFMA_BF16(B.m8[kd], sfa, ca);
      cb = MFMA_BF16(B.m8[kd + 4], sfb, cb);
    }
    f32x4 cacc;
#pragma unroll
    for (int r = 0; r < 4; r++) cacc[r] = ca[r] + cb[r];
    if (isU) {
      int cm = wc * 16 + quad * 4;
      uint2 o;
      o.x = cvt_pk_bf16(cacc[0], cacc[1]);
      o.y = cvt_pk_bf16(cacc[2], cacc[3]);
      *(uint2*)&Ubf[l15 * 40 + cm] = o;
    }
    barrier_lds_only();
    short8 bu = *(const short8*)&Ubf[l15 * 40 + quad * 8];
    if (!isU) {
      cacc = MFMA_BF16(B.af, bu, cacc);
#pragma unroll
      for (int rg = 0; rg < 4; rg++) {
        int l = i * 32 + wc * 16 + quad * 4 + rg;
        i64 row = ((i64)b_ * 1024 + l) * 4 + h_;
        dlt[row * 256 + j0 + l15] = cacc[rg];
        brcat[row * 1024 + 512 + j0 + l15] = f2bf(cacc[rg]);
      }
    }
#pragma unroll
    for (int dt = 0; dt < 4; dt++) accS[dt] = MFMA_BF16(B.kf[dt], bu, accS[dt]);
#pragma unroll
    for (int dt = 0; dt < 4; dt++) {
      uint2 o;
      o.x = cvt_pk_bf16(accS[dt][0], accS[dt][1]);
      o.y = cvt_pk_bf16(accS[dt][2], accS[dt][3]);
      *(uint2*)&Sbf[l15 * SROW + w * 64 + dt * 16 + quad * 4] = o;
    }
    barrier_lds_only();
  };

  ScanBuf b0, b1;
  load_chunk(0, b0);
#pragma unroll 1
  for (int ii = 0; ii < 16; ii++) {
    int i = ii * 2;
    load_chunk(i + 1, b1);
    process(i, b0);
    if (ii < 15) load_chunk(i + 2, b0);
    process(i + 1, b1);
  }
  __builtin_amdgcn_s_setprio(0);
}

// ---------------- FIR body ----------------
__device__ void fir2_body(
    int blk, const float* __restrict__ v,
    const float* __restrict__ f_s, const float* __restrict__ f_l,
    float* __restrict__ fs, float* __restrict__ fl, u16t* __restrict__ brcat) {
  int t = threadIdx.x;
  int b = blk >> 8, h = (blk >> 6) & 3, lc = blk & 63;
  int l0 = lc * 16;
  float flw[31], fsw[3];
  const float* flp = f_l + ((i64)h * 256 + t) * 31;
#pragma unroll
  for (int j = 0; j < 31; j++) flw[j] = flp[j];
  const float* fsp = f_s + ((i64)h * 256 + t) * 3;
#pragma unroll
  for (int j = 0; j < 3; j++) fsw[j] = fsp[j];
  float win[46];
#pragma unroll
  for (int r = 0; r < 46; r++) {
    int l = l0 - 30 + r;
    win[r] = (l >= 0) ? v[(((i64)b * 1024 + l) * 4 + h) * 256 + t] : 0.0f;
  }
#pragma unroll
  for (int i = 0; i < 16; i++) {
    float al = 0.0f;
#pragma unroll
    for (int j = 0; j < 31; j++) al += flw[j] * win[i + j];
    float as = fsw[0] * win[i + 28] + fsw[1] * win[i + 29] + fsw[2] * win[i + 30];
    i64 row = ((i64)b * 1024 + (l0 + i)) * 4 + h;
    fs[row * 256 + t] = as;
    fl[row * 256 + t] = al;
    brcat[row * 1024 + t] = f2bf(as);
    brcat[row * 1024 + 256 + t] = f2bf(al);
  }
}

// ---------------- mega2: scan(128) + fir(512) + W1/Wo transposes(2048) + wsum(24) ----
// scan co-scheduled with 2584 independent blocks so its serial chain hides.
// Transposes write into dead-vb region — mega2 launches after phaseA, safe.
__global__ __launch_bounds__(256) void mega2_kernel(
    const u16t* __restrict__ wbf, const u16t* __restrict__ knT,
    const float* __restrict__ u_g, const u16t* __restrict__ qnbf,
    const u16t* __restrict__ attnbf, float* __restrict__ dlt, u16t* __restrict__ brcat,
    const float* __restrict__ vbuf, const float* __restrict__ firs,
    const float* __restrict__ firl, float* __restrict__ fs, float* __restrict__ fl,
    const float* __restrict__ gW1, const float* __restrict__ Wo,
    u16t* __restrict__ W1hT, u16t* __restrict__ W1bT, u16t* __restrict__ WoT,
    float* __restrict__ wsum) {
  __shared__ __attribute__((aligned(16))) char smem[9728];
  int blk = blockIdx.x;
  if (blk < 128) {
    u16t* Sbf = (u16t*)smem;
    u16t* Ubf = Sbf + 16 * SROW;
    delta_scan_body(blk, wbf, knT, u_g, qnbf, attnbf, dlt, brcat, Sbf, Ubf);
  } else if (blk < 640) {
    fir2_body(blk - 128, vbuf, firs, firl, fs, fl, brcat);
  } else if (blk < 2688) {
    float (*tile)[33] = (float(*)[33])smem;
    int pb = blk - 640;
    if (pb < 1024) {
      int which = pb >> 9, bi = pb & 511;
      const float* in = gW1 + (which ? (i64)4096 * 512 : 0);
      transcast_body(in, 512, which ? W1bT : W1hT, 1024, bi & 15, bi >> 4, tile);
    } else {
      int bi = pb - 1024;
      transcast_body(Wo, 1024, WoT, 1024, bi & 31, bi >> 5, tile);
    }
  } else {
    int bi = blk - 2688;         // 24 blocks: 12 stats x 2 col-halves
    int s12 = bi >> 1, col = (bi & 1) * 256 + threadIdx.x;
    const float* p = gW1 + (i64)(1024 + s12 * 256) * 512 + col;
    float acc = 0.0f;
    for (int r = 0; r < 256; r++) acc += p[(i64)r * 512];
    wsum[s12 * 512 + col] = acc;
  }
}

// ---------------- gemm2: hbase gemm(64) + branchW gemm(256) ----------------
__global__ __launch_bounds__(256) void gemm2_kernel(
    const u16t* __restrict__ xbf, const u16t* __restrict__ W1hT,
    float* __restrict__ hbase,
    const u16t* __restrict__ brcat, const u16t* __restrict__ W1bT,
    float* __restrict__ branchW) {
  __shared__ u16t As[128 * 40];
  __shared__ u16t Bs[128 * 40];
  int blk = blockIdx.x;
  if (blk < 64) {
    gemm_bt_body(xbf, W1hT, hbase, 1024, 512, (blk & 3) * 128, (blk >> 2) * 128, As, Bs);
  } else {
    int bi = blk - 64;
    gemm_bt_body(brcat, W1bT, branchW, 1024, 512, (bi & 3) * 128, (bi >> 2) * 128, As, Bs);
  }
}

// ---------------- gate MLP tail + mix + RMS norm: WAVE-PER-ROW ----------------
// One row (256 elems) per wave, 4 elems/lane via float4. All reductions are
// 64-lane butterflies: ZERO __syncthreads, zero LDS. Softmax computed
// redundantly by all lanes (uniform). Replaces the barrier-chain block version
// (59 us, VALUBusy 45%, latency-bound on 4 block-reduce rounds + t0 serial).
__global__ __launch_bounds__(256) void gatemix_kernel(
    const float* __restrict__ hbase, const float* __restrict__ brW,
    const float* __restrict__ wsum,
    const float* __restrict__ gb1, const float* __restrict__ gW2,
    const float* __restrict__ gb2, const float* __restrict__ temp,
    const float* __restrict__ epsf,
    const float* __restrict__ fs, const float* __restrict__ fl,
    const float* __restrict__ dlt, const float* __restrict__ v,
    const float* __restrict__ onw, u16t* __restrict__ out) {
  int t = threadIdx.x, lane = t & 63, wv = t >> 6;
  int row = blockIdx.x * 4 + wv;      // (b*1024+l)*4+h
  int bl = row >> 2, h = row & 3;
  i64 base = (i64)row * 256 + lane * 4;
  float4 vfs = *(const float4*)(fs + base);
  float4 vfl = *(const float4*)(fl + base);
  float4 vdl = *(const float4*)(dlt + base);
  float4 vvv = *(const float4*)(v + base);
  // sums + sumsq for 4 branches, batched butterfly (ILP 8)
  float r8[8];
  r8[0] = vfs.x + vfs.y + vfs.z + vfs.w;
  r8[1] = vfs.x * vfs.x + vfs.y * vfs.y + vfs.z * vfs.z + vfs.w * vfs.w;
  r8[2] = vfl.x + vfl.y + vfl.z + vfl.w;
  r8[3] = vfl.x * vfl.x + vfl.y * vfl.y + vfl.z * vfl.z + vfl.w * vfl.w;
  r8[4] = vdl.x + vdl.y + vdl.z + vdl.w;
  r8[5] = vdl.x * vdl.x + vdl.y * vdl.y + vdl.z * vdl.z + vdl.w * vdl.w;
  r8[6] = vvv.x + vvv.y + vvv.z + vvv.w;
  r8[7] = vvv.x * vvv.x + vvv.y * vvv.y + vvv.z * vvv.z + vvv.w * vvv.w;
#pragma unroll
  for (int off = 1; off < 64; off <<= 1) {
#pragma unroll
    for (int i = 0; i < 8; i++) r8[i] += __shfl_xor(r8[i], off);
  }
  float m4[4];
  m4[0] = fmaxf(fmaxf(vfs.x, vfs.y), fmaxf(vfs.z, vfs.w));
  m4[1] = fmaxf(fmaxf(vfl.x, vfl.y), fmaxf(vfl.z, vfl.w));
  m4[2] = fmaxf(fmaxf(vdl.x, vdl.y), fmaxf(vdl.z, vdl.w));
  m4[3] = fmaxf(fmaxf(vvv.x, vvv.y), fmaxf(vvv.z, vvv.w));
#pragma unroll
  for (int off = 1; off < 64; off <<= 1) {
#pragma unroll
    for (int i = 0; i < 4; i++) m4[i] = fmaxf(m4[i], __shfl_xor(m4[i], off));
  }
  float st[12];
#pragma unroll
  for (int p = 0; p < 4; p++) {
    st[p * 3 + 0] = r8[p * 2] * (1.0f / 256.0f);
    st[p * 3 + 1] = sqrtf(fmaxf(r8[p * 2 + 1] * (1.0f / 256.0f), 1e-8f));
    st[p * 3 + 2] = m4[p];
  }
  // gate MLP tail: 8 outputs per lane (o = jj*64 + lane), coalesced
  float lg[4] = {0, 0, 0, 0};
#pragma unroll
  for (int jj = 0; jj < 8; jj++) {
    int o = jj * 64 + lane;
    float hm = hbase[(i64)bl * 512 + o] + brW[(i64)row * 512 + o] + gb1[o];
#pragma unroll
    for (int s = 0; s < 12; s++) hm += st[s] * wsum[s * 512 + o];
    float ge = 0.5f * hm * (1.0f + erff(hm * 0.70710678118654752f));
    float4 w2 = *(const float4*)(gW2 + o * 4);
    lg[0] += ge * w2.x; lg[1] += ge * w2.y; lg[2] += ge * w2.z; lg[3] += ge * w2.w;
  }
#pragma unroll
  for (int off = 1; off < 64; off <<= 1) {
#pragma unroll
    for (int i = 0; i < 4; i++) lg[i] += __shfl_xor(lg[i], off);
  }
  // softmax + floor: all lanes compute identically (no broadcast needed)
  float tt = fminf(fmaxf(temp[h], 0.2f), 10.0f);
  float l0 = (lg[0] + gb2[0]) / tt;
  float l1 = (lg[1] + gb2[1]) / tt;
  float l2 = (lg[2] + gb2[2]) / tt;
  float l3 = (lg[3] + gb2[3]) / tt;
  float m = fmaxf(fmaxf(l0, l1), fmaxf(l2, l3));
  float e0 = expf(l0 - m), e1 = expf(l1 - m), e2 = expf(l2 - m), e3 = expf(l3 - m);
  float ssum = e0 + e1 + e2 + e3;
  float w0 = e0 / ssum, w1 = e1 / ssum, w2 = e2 / ssum, w3 = e3 / ssum;
  w0 = fmaxf(w0, fminf(fmaxf(epsf[h * 4 + 0], 1e-7f), 0.1f));
  w1 = fmaxf(w1, fminf(fmaxf(epsf[h * 4 + 1], 1e-7f), 0.1f));
  w2 = fmaxf(w2, fminf(fmaxf(epsf[h * 4 + 2], 1e-7f), 0.1f));
  w3 = fmaxf(w3, fminf(fmaxf(epsf[h * 4 + 3], 1e-7f), 0.1f));
  float s2 = w0 + w1 + w2 + w3;
  float g0 = w0 / s2, g1 = w1 / s2, g2 = w2 / s2, g3 = w3 / s2;
  // mix + RMS
  float4 o4;
  o4.x = g0 * vfs.x + g1 * vfl.x + g2 * vdl.x + g3 * vvv.x;
  o4.y = g0 * vfs.y + g1 * vfl.y + g2 * vdl.y + g3 * vvv.y;
  o4.z = g0 * vfs.z + g1 * vfl.z + g2 * vdl.z + g3 * vvv.z;
  o4.w = g0 * vfs.w + g1 * vfl.w + g2 * vdl.w + g3 * vvv.w;
  float ss = o4.x * o4.x + o4.y * o4.y + o4.z * o4.z + o4.w * o4.w;
#pragma unroll
  for (int off = 1; off < 64; off <<= 1) ss += __shfl_xor(ss, off);
  float scale = rsqrtf(ss * (1.0f / 256.0f) + 1e-5f);
  float4 ow4 = *(const float4*)(onw + lane * 4);
  uint2 ow;
  ow.x = cvt_pk_bf16(o4.x * scale * ow4.x, o4.y * scale * ow4.y);
  ow.y = cvt_pk_bf16(o4.z * scale * ow4.z, o4.w * scale * ow4.w);
  *(uint2*)(out + (i64)bl * 1024 + h * 256 + lane * 4) = ow;
}

extern "C" void kernel_launch(void* const* d_in, const int* in_sizes, int n_in,
                              void* d_out, int out_size, void* d_ws, size_t ws_size,
                              hipStream_t stream) {
  (void)in_sizes; (void)n_in; (void)out_size; (void)ws_size;
  const float* x    = (const float*)d_in[0];
  const float* Wq   = (const float*)d_in[1];
  const float* Wk   = (const float*)d_in[2];
  const float* Wv   = (const float*)d_in[3];
  const float* Wb   = (const float*)d_in[4];
  const float* qcw  = (const float*)d_in[5];
  const float* kcw  = (const float*)d_in[6];
  const float* vcw  = (const float*)d_in[7];
  const float* gW1  = (const float*)d_in[8];
  const float* gb1  = (const float*)d_in[9];
  const float* gW2  = (const float*)d_in[10];
  const float* gb2  = (const float*)d_in[11];
  const float* temp = (const float*)d_in[12];
  const float* epsf = (const float*)d_in[13];
  const float* onw  = (const float*)d_in[14];
  const float* Wo   = (const float*)d_in[15];
  const float* firs = (const float*)d_in[16];
  const float* firl = (const float*)d_in[17];
  float* out = (float*)d_out;

  float* ws = (float*)d_ws;
  // ---- workspace map (float offsets); W1hT/W1bT/WoT share vb's region and
  // are only written AFTER phaseA (mega2) — r7/r8 NaN bug fix ----
  float* qkv_pre  = ws + 0;                       // 2048*3072 fp32 (dead after conv)
  float* branchW  = ws + 0;                       // 8192*512 fp32 (gemm2+)
  float* hbase    = ws + 4194304;                 // 2048*512 fp32 (gemm2+)
  u16t*  brcat    = (u16t*)(ws + 6291456);        // 8192*1024 bf16
  float* qbuf     = ws + 10485760; float* qn = qbuf;
  float* kbuf     = ws + 12582912; float* kn = kbuf;
  float* vbuf     = ws + 14680064;
  float* vb       = ws + 16777216;                // dead after phaseA
  u16t*  omix_bf  = (u16t*)(ws + 16777216);       // gatemix+
  u16t*  W1hT     = (u16t*)(ws + 17825792);       // mega2+ (inside dead vb)
  u16t*  W1bT     = (u16t*)(ws + 18087936);
  u16t*  WoT      = (u16t*)(ws + 18350080);
  float* kb       = ws + 18874368;                // dead after phaseA
  float* dlt      = ws + 18874368;                // scan output
  float* u_g      = ws + 20971520;
  u16t*  w_bf     = (u16t*)(ws + 23068672);
  u16t*  qn_bf    = (u16t*)(ws + 24117248);
  u16t*  knT      = (u16t*)(ws + 25165824);
  u16t*  attn_bf  = (u16t*)(ws + 26214400);
  float* fs       = ws + 26345472;
  float* fl       = ws + 28442624;
  u16t*  xbf      = (u16t*)(ws + 30539776);
  u16t*  WqkvT    = (u16t*)(ws + 31588352);
  float* betab    = ws + 33161216;                // 8192 fp32
  float* wsum     = ws + 33267712;

  // 1) prep: QKV weight transpose + x cast
  prep_kernel<<<5120, 256, 0, stream>>>(Wq, Wk, Wv, x, WqkvT, xbf);
  // 2) QKV GEMM
  gemm_bt_kernel<<<dim3(24, 16), 256, 0, stream>>>(xbf, WqkvT, qkv_pre, 1024, 3072);
  // 3) conv+silu (v also -> brcat col 768)
  conv_silu3_kernel<<<24576, 256, 0, stream>>>(qkv_pre, qcw, kcw, vcw, qbuf, kbuf, vbuf, brcat);
  // 4) beta + preprocess
  beta_kernel<<<2048, 256, 0, stream>>>(x, Wb, betab);
  preprocess_kernel<<<8192, 256, 0, stream>>>(qbuf, kbuf, vbuf, betab, qn, kn, vb, kb, qn_bf);
  // 5) phase A (last reader of vb/kb)
  phaseA_kernel<<<256, 256, 0, stream>>>(qn, kn, vb, kb, u_g, w_bf, attn_bf, knT);
  // 6) mega2: scan + FIR + W1/Wo transposes + wsum (scan co-scheduled again)
  mega2_kernel<<<2712, 256, 0, stream>>>(w_bf, knT, u_g, qn_bf, attn_bf, dlt, brcat,
                                         vbuf, firs, firl, fs, fl,
                                         gW1, Wo, W1hT, W1bT, WoT, wsum);
  // 7) gemm2: hbase GEMM + branchW GEMM
  gemm2_kernel<<<320, 256, 0, stream>>>(xbf, W1hT, hbase, brcat, W1bT, branchW);
  // 8) gate tail + mix + RMS (wave-per-row, no barriers)
  gatemix_kernel<<<2048, 256, 0, stream>>>(hbase, branchW, wsum, gb1, gW2, gb2,
                                           temp, epsf, fs, fl, dlt, vbuf, onw, omix_bf);
  // 9) final projection
  gemm_bt_kernel<<<dim3(8, 16), 256, 0, stream>>>(omix_bf, WoT, out, 1024, 1024);
}